// Round 5
// baseline (501.493 us; speedup 1.0000x reference)
//
#include <hip/hip_runtime.h>
#include <hip/hip_bf16.h>

typedef unsigned short u16;
typedef short s16x8 __attribute__((ext_vector_type(8)));
typedef float f32x4 __attribute__((ext_vector_type(4)));

#define EMB 768
#define NH 12
#define HD 64
#define BB 16
#define SS 1024
#define MTOK (BB*SS)      // 16384
#define NQKV (3*EMB)      // 2304
#define QSZ ((size_t)BB*NH*SS*HD)   // 12,582,912 elements
#define VROWS 80          // V^T padded: rows 0..63 = V, row 64 = ones, 65..79 junk

#define GLOBAL_AS const __attribute__((address_space(1))) void*
#define LDS_AS __attribute__((address_space(3))) void*

#if __has_builtin(__builtin_amdgcn_exp2f)
#define EXP2(x) __builtin_amdgcn_exp2f(x)
#else
#define EXP2(x) exp2f(x)
#endif

__device__ __forceinline__ u16 f2bf(float f){          // RNE
  unsigned u = __float_as_uint(f);
  u += 0x7FFFu + ((u >> 16) & 1u);
  return (u16)(u >> 16);
}
__device__ __forceinline__ u16 f2bf_trunc(float f){    // truncate (P only)
  return (u16)(__float_as_uint(f) >> 16);
}
__device__ __forceinline__ f32x4 mfma16(s16x8 a, s16x8 b, f32x4 c){
  return __builtin_amdgcn_mfma_f32_16x16x32_bf16(a, b, c, 0, 0, 0);
}

// ---------------- x: f32 -> bf16 bulk convert --------------------------------
__global__ __launch_bounds__(256) void convert_f32_bf16(
    const float4* __restrict__ in, ushort4* __restrict__ out, int n4){
  int i = blockIdx.x * 256 + threadIdx.x;
  if(i < n4){
    float4 f = in[i];
    ushort4 o;
    o.x = f2bf(f.x); o.y = f2bf(f.y); o.z = f2bf(f.z); o.w = f2bf(f.w);
    out[i] = o;
  }
}

// ---------------- fill V^T ones-row (d=64) -----------------------------------
__global__ __launch_bounds__(256) void ones_row(u16* __restrict__ Vt){
  int bh = blockIdx.x;
  ushort4 v; v.x = v.y = v.z = v.w = 0x3F80;   // bf16 1.0
  ((ushort4*)(Vt + ((size_t)bh * VROWS + 64) * SS))[threadIdx.x] = v;
}

// ---------------- transpose+convert [R,C] f32 -> [C,R] bf16 ------------------
__global__ void transpose_conv(const float* __restrict__ in, u16* __restrict__ out,
                               int R, int C){
  __shared__ u16 tile[32][33];
  int bx = blockIdx.x * 32, by = blockIdx.y * 32;
  int tx = threadIdx.x & 31, ty = threadIdx.x >> 5;
  #pragma unroll
  for(int i = 0; i < 32; i += 8)
    tile[ty + i][tx] = f2bf(in[(size_t)(by + ty + i) * C + bx + tx]);
  __syncthreads();
  #pragma unroll
  for(int i = 0; i < 32; i += 8)
    out[(size_t)(bx + ty + i) * R + by + tx] = tile[tx][ty + i];
}

// ---------------- 128x128 bf16 MFMA GEMM, K=768 ------------------------------
// MODE 0: qkv epilogue (scatter Q[bh,S,D], K[bh,S,D], V^T[bh,VROWS,S], bf16)
// MODE 1: C = A@B + bias -> out0 [M,768] f32
template<int MODE>
__global__ __launch_bounds__(256) void gemm_kernel(
    const u16* __restrict__ A, const u16* __restrict__ Bt,
    const float* __restrict__ bias,
    void* __restrict__ out0, u16* __restrict__ out1, u16* __restrict__ out2){
  const int K = 768;
  __shared__ u16 As[128*64];
  __shared__ u16 Bs[128*64];
  int tid = threadIdx.x;
  int m0 = blockIdx.y * 128, n0 = blockIdx.x * 128;
  int w = tid >> 6, lane = tid & 63, quad = lane >> 4, l15 = lane & 15;
  int wm = (w >> 1) * 64, wn = (w & 1) * 64;
  int rr = lane >> 3;          // row within a 1KB chunk-issue (0..7)
  int cp = lane & 7;           // 16B chunk position within row
  f32x4 acc[4][4] = {};

  for(int k0 = 0; k0 < K; k0 += 64){
    __syncthreads();
    #pragma unroll
    for(int it = 0; it < 4; ++it){
      int ci = it * 4 + w;
      int r  = ci * 8 + rr;
      int gc = (cp ^ (r & 7)) * 8;
      __builtin_amdgcn_global_load_lds(
          (GLOBAL_AS)(A + (size_t)(m0 + r) * K + k0 + gc),
          (LDS_AS)(As + ci * 512 + lane * 8), 16, 0, 0);
      __builtin_amdgcn_global_load_lds(
          (GLOBAL_AS)(Bt + (size_t)(n0 + r) * K + k0 + gc),
          (LDS_AS)(Bs + ci * 512 + lane * 8), 16, 0, 0);
    }
    __syncthreads();
    #pragma unroll
    for(int kk = 0; kk < 2; kk++){
      s16x8 a[4], b[4];
      int ch = ((kk * 4 + quad) ^ (l15 & 7)) * 8;
      #pragma unroll
      for(int i = 0; i < 4; i++){
        a[i] = *(const s16x8*)&As[(wm + i*16 + l15) * 64 + ch];
        b[i] = *(const s16x8*)&Bs[(wn + i*16 + l15) * 64 + ch];
      }
      #pragma unroll
      for(int mt = 0; mt < 4; mt++)
        #pragma unroll
        for(int nt = 0; nt < 4; nt++)
          acc[mt][nt] = mfma16(a[mt], b[nt], acc[mt][nt]);
    }
  }

  #pragma unroll
  for(int mt = 0; mt < 4; mt++){
    #pragma unroll
    for(int nt = 0; nt < 4; nt++){
      int n = n0 + wn + nt*16 + l15;
      float bv = bias[n];
      #pragma unroll
      for(int r = 0; r < 4; r++){
        int m = m0 + wm + mt*16 + quad*4 + r;
        float v = acc[mt][nt][r] + bv;
        if(MODE == 1){
          ((float*)out0)[(size_t)m * EMB + n] = v;
        } else {
          u16 hv = f2bf(v);
          int which = n / EMB, rem = n - which * EMB;
          int h = rem >> 6, d = rem & 63;
          int b = m >> 10, s = m & 1023;
          size_t bh = (size_t)(b * NH + h);
          if(which == 0)      ((u16*)out0)[(bh * SS + s) * HD + d] = hv;
          else if(which == 1) out1[(bh * SS + s) * HD + d] = hv;
          else                out2[(bh * VROWS + d) * SS + s] = hv;  // V^T
        }
      }
    }
  }
}

// ---------------- attention: block = (bh, 128 q-rows), no barriers -----------
// K,V fragments loaded directly from global (coalesced); fixed-max softmax
// (P = exp2(s*log2e/8 - 30*log2e)); row-sums via ones-row of V^T (d=64).
__global__ __launch_bounds__(256) void attn_kernel(
    const u16* __restrict__ Qws, const u16* __restrict__ Kws,
    const u16* __restrict__ Vtws, u16* __restrict__ attn){
  __shared__ __align__(16) u16 Ps[4][2][16][136];   // [wave][m][q][key]
  int tid = threadIdx.x;
  int w = tid >> 6, lane = tid & 63, quad = lane >> 4, l15 = lane & 15;
  int bh = blockIdx.x;                 // same-bh blocks -> same XCD (L2 reuse)
  int b = bh / NH, h = bh - b * NH;
  int q0 = blockIdx.y * 128 + w * 32;
  const u16* Qbase = Qws  + (size_t)bh * SS * HD;
  const u16* Kbase = Kws  + (size_t)bh * SS * HD;
  const u16* Vbase = Vtws + (size_t)bh * VROWS * SS;

  s16x8 aq[2][2];
  #pragma unroll
  for(int m = 0; m < 2; m++){
    int qrow = q0 + m*16 + l15;
    #pragma unroll
    for(int kk = 0; kk < 2; kk++)
      aq[m][kk] = *(const s16x8*)(Qbase + (size_t)qrow * HD + kk*32 + quad*8);
  }

  f32x4 o[2][5] = {};                 // [m][d-tile 0..3; 4 = row-sum]
  const float C1 = 0.125f * 1.44269504f;
  const float C0 = -30.0f * 1.44269504f;

  for(int kt = 0; kt < 8; ++kt){
    const u16* Kt = Kbase + (size_t)kt * 128 * HD;
    // scores -> exp -> P (per-wave LDS, C-layout -> A-layout)
    #pragma unroll
    for(int nt = 0; nt < 8; ++nt){
      s16x8 bk[2];
      #pragma unroll
      for(int kk = 0; kk < 2; kk++)
        bk[kk] = *(const s16x8*)(Kt + (size_t)(nt*16 + l15) * HD + kk*32 + quad*8);
      #pragma unroll
      for(int m = 0; m < 2; m++){
        f32x4 z = {};
        z = mfma16(aq[m][0], bk[0], z);
        z = mfma16(aq[m][1], bk[1], z);
        #pragma unroll
        for(int r = 0; r < 4; r++){
          float p = EXP2(z[r] * C1 + C0);
          Ps[w][m][quad*4 + r][nt*16 + l15] = f2bf_trunc(p);
        }
      }
    }
    // PV: o(2x16x64) += P(2x16x128) @ V(128x64); nt=4 tile = row sums
    const u16* Vt = Vbase + (size_t)kt * 128;
    #pragma unroll
    for(int k4 = 0; k4 < 4; k4++){
      s16x8 pa[2];
      #pragma unroll
      for(int m = 0; m < 2; m++)
        pa[m] = *(const s16x8*)&Ps[w][m][l15][k4*32 + quad*8];
      #pragma unroll
      for(int nt = 0; nt < 5; nt++){
        s16x8 vb = *(const s16x8*)(Vt + (size_t)(nt*16 + l15) * SS + k4*32 + quad*8);
        #pragma unroll
        for(int m = 0; m < 2; m++)
          o[m][nt] = mfma16(pa[m], vb, o[m][nt]);
      }
    }
  }

  // epilogue: out[b, s, h*64+d] = o/rowsum; rowsum r sits in lane quad*16, reg r
  #pragma unroll
  for(int m = 0; m < 2; m++){
    float inv[4];
    #pragma unroll
    for(int r = 0; r < 4; r++){
      float sv = __shfl(o[m][4][r], quad*16, 64);
      inv[r] = 1.0f / sv;
    }
    #pragma unroll
    for(int nt = 0; nt < 4; nt++)
      #pragma unroll
      for(int r = 0; r < 4; r++){
        int srow = q0 + m*16 + quad*4 + r;
        size_t base = ((size_t)(b * SS + srow)) * EMB + h * HD;
        attn[base + nt*16 + l15] = f2bf(o[m][nt][r] * inv[r]);
      }
  }
}

extern "C" void kernel_launch(void* const* d_in, const int* in_sizes, int n_in,
                              void* d_out, int out_size, void* d_ws, size_t ws_size,
                              hipStream_t stream){
  const float* x      = (const float*)d_in[0];
  const float* qkv_w  = (const float*)d_in[1];
  const float* qkv_b  = (const float*)d_in[2];
  const float* proj_w = (const float*)d_in[3];
  const float* proj_b = (const float*)d_in[4];

  char* ws = (char*)d_ws;
  u16* qkv_wT  = (u16*)ws; ws += (size_t)NQKV * EMB * 2;   // [2304,768] bf16
  u16* proj_wT = (u16*)ws; ws += (size_t)EMB * EMB * 2;    // [768,768] bf16
  u16* x_bf = (u16*)ws; ws += QSZ * 2;   // [16384,768] bf16; reused as attn out
  u16* Qws  = (u16*)ws; ws += QSZ * 2;                     // [bh,S,D]
  u16* Kws  = (u16*)ws; ws += QSZ * 2;                     // [bh,S,D]
  u16* Vtws = (u16*)ws; ws += (size_t)BB * NH * VROWS * SS * 2;  // [bh,80,S]
  u16* attn = x_bf;

  int n4 = (int)(QSZ / 4);
  convert_f32_bf16<<<(n4 + 255) / 256, 256, 0, stream>>>(
      (const float4*)x, (ushort4*)x_bf, n4);
  transpose_conv<<<dim3(NQKV/32, EMB/32), 256, 0, stream>>>(qkv_w, qkv_wT, EMB, NQKV);
  transpose_conv<<<dim3(EMB/32, EMB/32), 256, 0, stream>>>(proj_w, proj_wT, EMB, EMB);
  ones_row<<<BB*NH, 256, 0, stream>>>(Vtws);
  gemm_kernel<0><<<dim3(NQKV/128, MTOK/128), 256, 0, stream>>>(
      x_bf, qkv_wT, qkv_b, Qws, Kws, Vtws);
  attn_kernel<<<dim3(BB*NH, SS/128), 256, 0, stream>>>(Qws, Kws, Vtws, attn);
  gemm_kernel<1><<<dim3(EMB/128, MTOK/128), 256, 0, stream>>>(
      attn, proj_wT, proj_b, d_out, nullptr, nullptr);
}

// Round 6
// 333.074 us; speedup vs baseline: 1.5057x; 1.5057x over previous
//
#include <hip/hip_runtime.h>
#include <hip/hip_bf16.h>

typedef unsigned short u16;
typedef short s16x8 __attribute__((ext_vector_type(8)));
typedef float f32x4 __attribute__((ext_vector_type(4)));

#define EMB 768
#define NH 12
#define HD 64
#define BB 16
#define SS 1024
#define MTOK (BB*SS)      // 16384
#define NQKV (3*EMB)      // 2304
#define QSZ ((size_t)BB*NH*SS*HD)   // 12,582,912 elements

#define GLOBAL_AS const __attribute__((address_space(1))) void*
#define LDS_AS __attribute__((address_space(3))) void*

#if __has_builtin(__builtin_amdgcn_exp2f)
#define EXP2(x) __builtin_amdgcn_exp2f(x)
#else
#define EXP2(x) exp2f(x)
#endif

__device__ __forceinline__ u16 f2bf(float f){          // RNE
  unsigned u = __float_as_uint(f);
  u += 0x7FFFu + ((u >> 16) & 1u);
  return (u16)(u >> 16);
}
__device__ __forceinline__ u16 f2bf_trunc(float f){    // truncate (P only)
  return (u16)(__float_as_uint(f) >> 16);
}
__device__ __forceinline__ f32x4 mfma16(s16x8 a, s16x8 b, f32x4 c){
  return __builtin_amdgcn_mfma_f32_16x16x32_bf16(a, b, c, 0, 0, 0);
}

// ---------------- x: f32 -> bf16 bulk convert --------------------------------
__global__ __launch_bounds__(256) void convert_f32_bf16(
    const float4* __restrict__ in, ushort4* __restrict__ out, int n4){
  int i = blockIdx.x * 256 + threadIdx.x;
  if(i < n4){
    float4 f = in[i];
    ushort4 o;
    o.x = f2bf(f.x); o.y = f2bf(f.y); o.z = f2bf(f.z); o.w = f2bf(f.w);
    out[i] = o;
  }
}

// ---------------- transpose+convert [R,C] f32 -> [C,R] bf16 ------------------
__global__ void transpose_conv(const float* __restrict__ in, u16* __restrict__ out,
                               int R, int C){
  __shared__ u16 tile[32][33];
  int bx = blockIdx.x * 32, by = blockIdx.y * 32;
  int tx = threadIdx.x & 31, ty = threadIdx.x >> 5;
  #pragma unroll
  for(int i = 0; i < 32; i += 8)
    tile[ty + i][tx] = f2bf(in[(size_t)(by + ty + i) * C + bx + tx]);
  __syncthreads();
  #pragma unroll
  for(int i = 0; i < 32; i += 8)
    out[(size_t)(bx + ty + i) * R + by + tx] = tile[tx][ty + i];
}

// ---------------- 128x128 bf16 MFMA GEMM, K=768 ------------------------------
// MODE 0: qkv epilogue (scatter Q[bh,S,D], K[bh,S,D], V^T[bh,D,S], bf16)
// MODE 1: C = A@B + bias -> out0 [M,768] f32
template<int MODE>
__global__ __launch_bounds__(256) void gemm_kernel(
    const u16* __restrict__ A, const u16* __restrict__ Bt,
    const float* __restrict__ bias,
    void* __restrict__ out0, u16* __restrict__ out1, u16* __restrict__ out2){
  const int K = 768;
  __shared__ u16 As[128*64];
  __shared__ u16 Bs[128*64];
  int tid = threadIdx.x;
  int m0 = blockIdx.y * 128, n0 = blockIdx.x * 128;
  int w = tid >> 6, lane = tid & 63, quad = lane >> 4, l15 = lane & 15;
  int wm = (w >> 1) * 64, wn = (w & 1) * 64;
  int rr = lane >> 3;          // row within a 1KB chunk-issue (0..7)
  int cp = lane & 7;           // 16B chunk position within row
  f32x4 acc[4][4] = {};

  for(int k0 = 0; k0 < K; k0 += 64){
    __syncthreads();
    #pragma unroll
    for(int it = 0; it < 4; ++it){
      int ci = it * 4 + w;
      int r  = ci * 8 + rr;
      int gc = (cp ^ (r & 7)) * 8;
      __builtin_amdgcn_global_load_lds(
          (GLOBAL_AS)(A + (size_t)(m0 + r) * K + k0 + gc),
          (LDS_AS)(As + ci * 512 + lane * 8), 16, 0, 0);
      __builtin_amdgcn_global_load_lds(
          (GLOBAL_AS)(Bt + (size_t)(n0 + r) * K + k0 + gc),
          (LDS_AS)(Bs + ci * 512 + lane * 8), 16, 0, 0);
    }
    __syncthreads();
    #pragma unroll
    for(int kk = 0; kk < 2; kk++){
      s16x8 a[4], b[4];
      int ch = ((kk * 4 + quad) ^ (l15 & 7)) * 8;
      #pragma unroll
      for(int i = 0; i < 4; i++){
        a[i] = *(const s16x8*)&As[(wm + i*16 + l15) * 64 + ch];
        b[i] = *(const s16x8*)&Bs[(wn + i*16 + l15) * 64 + ch];
      }
      #pragma unroll
      for(int mt = 0; mt < 4; mt++)
        #pragma unroll
        for(int nt = 0; nt < 4; nt++)
          acc[mt][nt] = mfma16(a[mt], b[nt], acc[mt][nt]);
    }
  }

  #pragma unroll
  for(int mt = 0; mt < 4; mt++){
    #pragma unroll
    for(int nt = 0; nt < 4; nt++){
      int n = n0 + wn + nt*16 + l15;
      float bv = bias[n];
      #pragma unroll
      for(int r = 0; r < 4; r++){
        int m = m0 + wm + mt*16 + quad*4 + r;
        float v = acc[mt][nt][r] + bv;
        if(MODE == 1){
          ((float*)out0)[(size_t)m * EMB + n] = v;
        } else {
          u16 hv = f2bf(v);
          int which = n / EMB, rem = n - which * EMB;
          int h = rem >> 6, d = rem & 63;
          int b = m >> 10, s = m & 1023;
          size_t bh = (size_t)(b * NH + h);
          if(which == 0)      ((u16*)out0)[(bh * SS + s) * HD + d] = hv;
          else if(which == 1) out1[(bh * SS + s) * HD + d] = hv;
          else                out2[(bh * HD + d) * SS + s] = hv;   // V^T
        }
      }
    }
  }
}

// ---------------- attention: block = (bh, 128 q-rows) ------------------------
// 64-key tiles staged via global_load_lds (XOR-swizzled); fixed-max softmax
// P = exp2(s*log2e/8 - 30*log2e); row-sums in registers (shfl at epilogue).
__global__ __launch_bounds__(256) void attn_kernel(
    const u16* __restrict__ Qws, const u16* __restrict__ Kws,
    const u16* __restrict__ Vtws, u16* __restrict__ attn){
  __shared__ u16 Ks[64*64];                       // [key][d]   8 KB
  __shared__ u16 Vs[64*64];                       // [d][key]   8 KB
  __shared__ __align__(16) u16 Ps[4][2][16][76];  // [wave][m][q][key] 19 KB
  int tid = threadIdx.x;
  int w = tid >> 6, lane = tid & 63, quad = lane >> 4, l15 = lane & 15;
  int bh = blockIdx.x;                 // x=bh: all q-blocks of a bh -> same XCD
  int b = bh / NH, h = bh - b * NH;
  int q0 = blockIdx.y * 128 + w * 32;
  const u16* Qbase = Qws  + (size_t)bh * SS * HD;
  const u16* Kbase = Kws  + (size_t)bh * SS * HD;
  const u16* Vbase = Vtws + (size_t)bh * HD * SS;

  s16x8 aq[2][2];
  #pragma unroll
  for(int m = 0; m < 2; m++){
    int qrow = q0 + m*16 + l15;
    #pragma unroll
    for(int kk = 0; kk < 2; kk++)
      aq[m][kk] = *(const s16x8*)(Qbase + (size_t)qrow * HD + kk*32 + quad*8);
  }

  f32x4 o[2][4] = {};
  float psum[2][4] = {};
  const float C1 = 0.125f * 1.44269504f;
  const float C0 = -30.0f * 1.44269504f;

  int krr = lane >> 3, kcp = lane & 7;   // staging decode: 8 rows x 8 chunks

  for(int kt = 0; kt < 16; ++kt){        // 64 keys per iteration
    __syncthreads();
    #pragma unroll
    for(int it = 0; it < 2; ++it){
      int ins = it * 4 + w;              // 0..7
      int r   = ins * 8 + krr;           // 0..63
      // K tile: rows = keys, 64 d each
      int gck = (kcp ^ (r & 7)) * 8;
      __builtin_amdgcn_global_load_lds(
          (GLOBAL_AS)(Kbase + (size_t)(kt*64 + r) * HD + gck),
          (LDS_AS)(Ks + ins * 512 + lane * 8), 16, 0, 0);
      // V^T tile: rows = d, 64 keys each
      __builtin_amdgcn_global_load_lds(
          (GLOBAL_AS)(Vbase + (size_t)r * SS + kt*64 + gck),
          (LDS_AS)(Vs + ins * 512 + lane * 8), 16, 0, 0);
    }
    __syncthreads();

    // scores + exp + P  (4 key-tiles of 16)
    #pragma unroll
    for(int nt = 0; nt < 4; ++nt){
      s16x8 bk[2];
      #pragma unroll
      for(int kk = 0; kk < 2; kk++){
        int ch = ((kk*4 + quad) ^ (l15 & 7)) * 8;
        bk[kk] = *(const s16x8*)&Ks[(nt*16 + l15) * 64 + ch];
      }
      #pragma unroll
      for(int m = 0; m < 2; m++){
        f32x4 z = {};
        z = mfma16(aq[m][0], bk[0], z);
        z = mfma16(aq[m][1], bk[1], z);
        #pragma unroll
        for(int r = 0; r < 4; r++){
          float p = EXP2(z[r] * C1 + C0);
          psum[m][r] += p;
          Ps[w][m][quad*4 + r][nt*16 + l15] = f2bf_trunc(p);
        }
      }
    }
    // PV: o(2x16x64) += P(2x16x64) @ V(64x64)
    #pragma unroll
    for(int k4 = 0; k4 < 2; k4++){
      s16x8 pa[2];
      #pragma unroll
      for(int m = 0; m < 2; m++)
        pa[m] = *(const s16x8*)&Ps[w][m][l15][k4*32 + quad*8];
      #pragma unroll
      for(int nt = 0; nt < 4; nt++){
        int ch = ((k4*4 + quad) ^ (l15 & 7)) * 8;
        s16x8 vb = *(const s16x8*)&Vs[(nt*16 + l15) * 64 + ch];
        #pragma unroll
        for(int m = 0; m < 2; m++)
          o[m][nt] = mfma16(pa[m], vb, o[m][nt]);
      }
    }
  }

  // epilogue: out[b, s, h*64+d] = o / rowsum
  #pragma unroll
  for(int m = 0; m < 2; m++){
    #pragma unroll
    for(int r = 0; r < 4; r++){
      float s = psum[m][r];
      s += __shfl_xor(s, 1, 64);
      s += __shfl_xor(s, 2, 64);
      s += __shfl_xor(s, 4, 64);
      s += __shfl_xor(s, 8, 64);
      float inv = 1.0f / s;
      int srow = q0 + m*16 + quad*4 + r;
      size_t base = ((size_t)(b * SS + srow)) * EMB + h * HD;
      #pragma unroll
      for(int nt = 0; nt < 4; nt++)
        attn[base + nt*16 + l15] = f2bf(o[m][nt][r] * inv);
    }
  }
}

extern "C" void kernel_launch(void* const* d_in, const int* in_sizes, int n_in,
                              void* d_out, int out_size, void* d_ws, size_t ws_size,
                              hipStream_t stream){
  const float* x      = (const float*)d_in[0];
  const float* qkv_w  = (const float*)d_in[1];
  const float* qkv_b  = (const float*)d_in[2];
  const float* proj_w = (const float*)d_in[3];
  const float* proj_b = (const float*)d_in[4];

  char* ws = (char*)d_ws;
  u16* qkv_wT  = (u16*)ws; ws += (size_t)NQKV * EMB * 2;   // [2304,768] bf16
  u16* proj_wT = (u16*)ws; ws += (size_t)EMB * EMB * 2;    // [768,768] bf16
  u16* x_bf = (u16*)ws; ws += QSZ * 2;   // [16384,768] bf16; reused as attn out
  u16* Qws  = (u16*)ws; ws += QSZ * 2;                     // [bh,S,D]
  u16* Kws  = (u16*)ws; ws += QSZ * 2;                     // [bh,S,D]
  u16* Vtws = (u16*)ws; ws += QSZ * 2;                     // [bh,D,S]
  u16* attn = x_bf;

  int n4 = (int)(QSZ / 4);
  convert_f32_bf16<<<(n4 + 255) / 256, 256, 0, stream>>>(
      (const float4*)x, (ushort4*)x_bf, n4);
  transpose_conv<<<dim3(NQKV/32, EMB/32), 256, 0, stream>>>(qkv_w, qkv_wT, EMB, NQKV);
  transpose_conv<<<dim3(EMB/32, EMB/32), 256, 0, stream>>>(proj_w, proj_wT, EMB, EMB);
  gemm_kernel<0><<<dim3(NQKV/128, MTOK/128), 256, 0, stream>>>(
      x_bf, qkv_wT, qkv_b, Qws, Kws, Vtws);
  attn_kernel<<<dim3(BB*NH, SS/128), 256, 0, stream>>>(Qws, Kws, Vtws, attn);
  gemm_kernel<1><<<dim3(EMB/128, MTOK/128), 256, 0, stream>>>(
      attn, proj_wT, proj_b, d_out, nullptr, nullptr);
}

// Round 7
// 329.372 us; speedup vs baseline: 1.5226x; 1.0112x over previous
//
#include <hip/hip_runtime.h>
#include <hip/hip_bf16.h>

typedef unsigned short u16;
typedef short s16x8 __attribute__((ext_vector_type(8)));
typedef float f32x4 __attribute__((ext_vector_type(4)));

#define EMB 768
#define NH 12
#define HD 64
#define BB 16
#define SS 1024
#define MTOK (BB*SS)      // 16384
#define NQKV (3*EMB)      // 2304
#define QSZ ((size_t)BB*NH*SS*HD)   // 12,582,912 elements

#define GLOBAL_AS const __attribute__((address_space(1))) void*
#define LDS_AS __attribute__((address_space(3))) void*

#if __has_builtin(__builtin_amdgcn_exp2f)
#define EXP2(x) __builtin_amdgcn_exp2f(x)
#else
#define EXP2(x) exp2f(x)
#endif

__device__ __forceinline__ u16 f2bf(float f){          // RNE
  unsigned u = __float_as_uint(f);
  u += 0x7FFFu + ((u >> 16) & 1u);
  return (u16)(u >> 16);
}
__device__ __forceinline__ u16 f2bf_trunc(float f){    // truncate (P only)
  return (u16)(__float_as_uint(f) >> 16);
}
__device__ __forceinline__ f32x4 mfma16(s16x8 a, s16x8 b, f32x4 c){
  return __builtin_amdgcn_mfma_f32_16x16x32_bf16(a, b, c, 0, 0, 0);
}

// ---------------- x: f32 -> bf16 bulk convert --------------------------------
__global__ __launch_bounds__(256) void convert_f32_bf16(
    const float4* __restrict__ in, ushort4* __restrict__ out, int n4){
  int i = blockIdx.x * 256 + threadIdx.x;
  if(i < n4){
    float4 f = in[i];
    ushort4 o;
    o.x = f2bf(f.x); o.y = f2bf(f.y); o.z = f2bf(f.z); o.w = f2bf(f.w);
    out[i] = o;
  }
}

// ---------------- transpose+convert [R,C] f32 -> [C,R] bf16 ------------------
__global__ void transpose_conv(const float* __restrict__ in, u16* __restrict__ out,
                               int R, int C){
  __shared__ u16 tile[32][33];
  int bx = blockIdx.x * 32, by = blockIdx.y * 32;
  int tx = threadIdx.x & 31, ty = threadIdx.x >> 5;
  #pragma unroll
  for(int i = 0; i < 32; i += 8)
    tile[ty + i][tx] = f2bf(in[(size_t)(by + ty + i) * C + bx + tx]);
  __syncthreads();
  #pragma unroll
  for(int i = 0; i < 32; i += 8)
    out[(size_t)(bx + ty + i) * R + by + tx] = tile[tx][ty + i];
}

// ---------------- 128x128 bf16 MFMA GEMM, K=768, double-buffered -------------
// MODE 0: qkv epilogue (scatter Q[bh,S,D], K[bh,S,D], V^T[bh,D,S], bf16)
// MODE 1: C = A@B + bias -> out0 [M,768] f32
template<int MODE>
__global__ __launch_bounds__(256) void gemm_kernel(
    const u16* __restrict__ A, const u16* __restrict__ Bt,
    const float* __restrict__ bias,
    void* __restrict__ out0, u16* __restrict__ out1, u16* __restrict__ out2){
  const int K = 768;
  __shared__ u16 As[2][128*64];
  __shared__ u16 Bs[2][128*64];
  int tid = threadIdx.x;
  int m0 = blockIdx.y * 128, n0 = blockIdx.x * 128;
  int w = tid >> 6, lane = tid & 63, quad = lane >> 4, l15 = lane & 15;
  int wm = (w >> 1) * 64, wn = (w & 1) * 64;
  int rr = lane >> 3;          // row within a 1KB chunk-issue (0..7)
  int cp = lane & 7;           // 16B chunk position within row
  f32x4 acc[4][4] = {};

  auto stage = [&](int p, int k0){
    #pragma unroll
    for(int it = 0; it < 4; ++it){
      int ci = it * 4 + w;
      int r  = ci * 8 + rr;
      int gc = (cp ^ (r & 7)) * 8;
      __builtin_amdgcn_global_load_lds(
          (GLOBAL_AS)(A + (size_t)(m0 + r) * K + k0 + gc),
          (LDS_AS)(As[p] + ci * 512 + lane * 8), 16, 0, 0);
      __builtin_amdgcn_global_load_lds(
          (GLOBAL_AS)(Bt + (size_t)(n0 + r) * K + k0 + gc),
          (LDS_AS)(Bs[p] + ci * 512 + lane * 8), 16, 0, 0);
    }
  };

  stage(0, 0);
  int p = 0;
  for(int k0 = 0; k0 < K; k0 += 64){
    __syncthreads();                       // drains stage(p); publishes buf p
    if(k0 + 64 < K) stage(p ^ 1, k0 + 64); // async prefetch overlaps compute
    #pragma unroll
    for(int kk = 0; kk < 2; kk++){
      s16x8 a[4], b[4];
      int ch = ((kk * 4 + quad) ^ (l15 & 7)) * 8;
      #pragma unroll
      for(int i = 0; i < 4; i++){
        a[i] = *(const s16x8*)&As[p][(wm + i*16 + l15) * 64 + ch];
        b[i] = *(const s16x8*)&Bs[p][(wn + i*16 + l15) * 64 + ch];
      }
      #pragma unroll
      for(int mt = 0; mt < 4; mt++)
        #pragma unroll
        for(int nt = 0; nt < 4; nt++)
          acc[mt][nt] = mfma16(a[mt], b[nt], acc[mt][nt]);
    }
    p ^= 1;
  }

  #pragma unroll
  for(int mt = 0; mt < 4; mt++){
    #pragma unroll
    for(int nt = 0; nt < 4; nt++){
      int n = n0 + wn + nt*16 + l15;
      float bv = bias[n];
      #pragma unroll
      for(int r = 0; r < 4; r++){
        int m = m0 + wm + mt*16 + quad*4 + r;
        float v = acc[mt][nt][r] + bv;
        if(MODE == 1){
          ((float*)out0)[(size_t)m * EMB + n] = v;
        } else {
          u16 hv = f2bf(v);
          int which = n / EMB, rem = n - which * EMB;
          int h = rem >> 6, d = rem & 63;
          int b = m >> 10, s = m & 1023;
          size_t bh = (size_t)(b * NH + h);
          if(which == 0)      ((u16*)out0)[(bh * SS + s) * HD + d] = hv;
          else if(which == 1) out1[(bh * SS + s) * HD + d] = hv;
          else                out2[(bh * HD + d) * SS + s] = hv;   // V^T
        }
      }
    }
  }
}

// ---------------- attention: block = (bh, 128 q-rows), double-buffered -------
// 64-key tiles staged via global_load_lds (XOR-swizzled); fixed-max softmax
// P = exp2(s*log2e/8 - 30*log2e); row-sums in registers (shfl at epilogue).
__global__ __launch_bounds__(256) void attn_kernel(
    const u16* __restrict__ Qws, const u16* __restrict__ Kws,
    const u16* __restrict__ Vtws, u16* __restrict__ attn){
  __shared__ u16 Ks[2][64*64];                    // [key][d]   16 KB
  __shared__ u16 Vs[2][64*64];                    // [d][key]   16 KB
  __shared__ __align__(16) u16 Ps[4][2][16][76];  // [wave][m][q][key] 19 KB
  int tid = threadIdx.x;
  int w = tid >> 6, lane = tid & 63, quad = lane >> 4, l15 = lane & 15;
  int bh = blockIdx.x;                 // x=bh: all q-blocks of a bh -> same XCD
  int b = bh / NH, h = bh - b * NH;
  int q0 = blockIdx.y * 128 + w * 32;
  const u16* Qbase = Qws  + (size_t)bh * SS * HD;
  const u16* Kbase = Kws  + (size_t)bh * SS * HD;
  const u16* Vbase = Vtws + (size_t)bh * HD * SS;

  s16x8 aq[2][2];
  #pragma unroll
  for(int m = 0; m < 2; m++){
    int qrow = q0 + m*16 + l15;
    #pragma unroll
    for(int kk = 0; kk < 2; kk++)
      aq[m][kk] = *(const s16x8*)(Qbase + (size_t)qrow * HD + kk*32 + quad*8);
  }

  f32x4 o[2][4] = {};
  float psum[2][4] = {};
  const float C1 = 0.125f * 1.44269504f;
  const float C0 = -30.0f * 1.44269504f;

  int krr = lane >> 3, kcp = lane & 7;   // staging decode: 8 rows x 8 chunks

  auto stageKV = [&](int p, int kt){
    #pragma unroll
    for(int it = 0; it < 2; ++it){
      int ins = it * 4 + w;              // 0..7
      int r   = ins * 8 + krr;           // 0..63
      int gck = (kcp ^ (r & 7)) * 8;
      __builtin_amdgcn_global_load_lds(
          (GLOBAL_AS)(Kbase + (size_t)(kt*64 + r) * HD + gck),
          (LDS_AS)(Ks[p] + ins * 512 + lane * 8), 16, 0, 0);
      __builtin_amdgcn_global_load_lds(
          (GLOBAL_AS)(Vbase + (size_t)r * SS + kt*64 + gck),
          (LDS_AS)(Vs[p] + ins * 512 + lane * 8), 16, 0, 0);
    }
  };

  stageKV(0, 0);
  int p = 0;
  for(int kt = 0; kt < 16; ++kt){        // 64 keys per iteration
    __syncthreads();                     // drains stage(p); publishes buf p
    if(kt < 15) stageKV(p ^ 1, kt + 1);  // prefetch overlaps compute

    // scores + exp + P  (4 key-tiles of 16)
    #pragma unroll
    for(int nt = 0; nt < 4; ++nt){
      s16x8 bk[2];
      #pragma unroll
      for(int kk = 0; kk < 2; kk++){
        int ch = ((kk*4 + quad) ^ (l15 & 7)) * 8;
        bk[kk] = *(const s16x8*)&Ks[p][(nt*16 + l15) * 64 + ch];
      }
      #pragma unroll
      for(int m = 0; m < 2; m++){
        f32x4 z = {};
        z = mfma16(aq[m][0], bk[0], z);
        z = mfma16(aq[m][1], bk[1], z);
        #pragma unroll
        for(int r = 0; r < 4; r++){
          float pv = EXP2(z[r] * C1 + C0);
          psum[m][r] += pv;
          Ps[w][m][quad*4 + r][nt*16 + l15] = f2bf_trunc(pv);
        }
      }
    }
    // PV: o(2x16x64) += P(2x16x64) @ V(64x64)
    #pragma unroll
    for(int k4 = 0; k4 < 2; k4++){
      s16x8 pa[2];
      #pragma unroll
      for(int m = 0; m < 2; m++)
        pa[m] = *(const s16x8*)&Ps[w][m][l15][k4*32 + quad*8];
      #pragma unroll
      for(int nt = 0; nt < 4; nt++){
        int ch = ((k4*4 + quad) ^ (l15 & 7)) * 8;
        s16x8 vb = *(const s16x8*)&Vs[p][(nt*16 + l15) * 64 + ch];
        #pragma unroll
        for(int m = 0; m < 2; m++)
          o[m][nt] = mfma16(pa[m], vb, o[m][nt]);
      }
    }
    p ^= 1;
  }

  // epilogue: out[b, s, h*64+d] = o / rowsum
  #pragma unroll
  for(int m = 0; m < 2; m++){
    #pragma unroll
    for(int r = 0; r < 4; r++){
      float s = psum[m][r];
      s += __shfl_xor(s, 1, 64);
      s += __shfl_xor(s, 2, 64);
      s += __shfl_xor(s, 4, 64);
      s += __shfl_xor(s, 8, 64);
      float inv = 1.0f / s;
      int srow = q0 + m*16 + quad*4 + r;
      size_t base = ((size_t)(b * SS + srow)) * EMB + h * HD;
      #pragma unroll
      for(int nt = 0; nt < 4; nt++)
        attn[base + nt*16 + l15] = f2bf(o[m][nt][r] * inv);
    }
  }
}

extern "C" void kernel_launch(void* const* d_in, const int* in_sizes, int n_in,
                              void* d_out, int out_size, void* d_ws, size_t ws_size,
                              hipStream_t stream){
  const float* x      = (const float*)d_in[0];
  const float* qkv_w  = (const float*)d_in[1];
  const float* qkv_b  = (const float*)d_in[2];
  const float* proj_w = (const float*)d_in[3];
  const float* proj_b = (const float*)d_in[4];

  char* ws = (char*)d_ws;
  u16* qkv_wT  = (u16*)ws; ws += (size_t)NQKV * EMB * 2;   // [2304,768] bf16
  u16* proj_wT = (u16*)ws; ws += (size_t)EMB * EMB * 2;    // [768,768] bf16
  u16* x_bf = (u16*)ws; ws += QSZ * 2;   // [16384,768] bf16; reused as attn out
  u16* Qws  = (u16*)ws; ws += QSZ * 2;                     // [bh,S,D]
  u16* Kws  = (u16*)ws; ws += QSZ * 2;                     // [bh,S,D]
  u16* Vtws = (u16*)ws; ws += QSZ * 2;                     // [bh,D,S]
  u16* attn = x_bf;

  int n4 = (int)(QSZ / 4);
  convert_f32_bf16<<<(n4 + 255) / 256, 256, 0, stream>>>(
      (const float4*)x, (ushort4*)x_bf, n4);
  transpose_conv<<<dim3(NQKV/32, EMB/32), 256, 0, stream>>>(qkv_w, qkv_wT, EMB, NQKV);
  transpose_conv<<<dim3(EMB/32, EMB/32), 256, 0, stream>>>(proj_w, proj_wT, EMB, EMB);
  gemm_kernel<0><<<dim3(NQKV/128, MTOK/128), 256, 0, stream>>>(
      x_bf, qkv_wT, qkv_b, Qws, Kws, Vtws);
  attn_kernel<<<dim3(BB*NH, SS/128), 256, 0, stream>>>(Qws, Kws, Vtws, attn);
  gemm_kernel<1><<<dim3(EMB/128, MTOK/128), 256, 0, stream>>>(
      attn, proj_wT, proj_b, d_out, nullptr, nullptr);
}